// Round 1
// baseline (132.358 us; speedup 1.0000x reference)
//
#include <hip/hip_runtime.h>
#include <hip/hip_bf16.h>

typedef __attribute__((ext_vector_type(8))) short bf16x8;
typedef __attribute__((ext_vector_type(4))) float f32x4;

// ---------------------------------------------------------------------------
// Problem geometry (fixed): B=2, C=64, H=W=64, N=4096, dk=8.
// Key identity: sobel weights are broadcast over [C,C,3,3] -> every conv
// output channel equals conv(channel-sum, 3x3). 1x1 conv then makes keys/
// queries affine in a single scalar field e[n]:
//   xq[n,d]  = A_d*eq[n] + bq_d,   xk[d,m] = C_d*e[m] + bk_d
//   logits[n,m] = (alpha*eq[n]+gamma)*e[m] + const(n)   (const drops in softmax)
// So attn row m = softmax_n( t_m * e[n] ),  t_m = alpha*eq[m]+gamma, and the
// row max is t*e_max (t>0) or t*e_min (t<0) -> K-split partials just add.
// ---------------------------------------------------------------------------

// K0: reduce 1x1-conv weights to scalars alpha/gamma, init min/max slots.
__global__ void k0_scalars(const float* __restrict__ w1_vi, const float* __restrict__ b1_vi,
                           const float* __restrict__ w1_q, const float* __restrict__ b1_q,
                           const float* __restrict__ w1_ir, const float* __restrict__ b1_ir,
                           float* __restrict__ scal) {
    __shared__ float Ad[8], Cv[8], Ci[8], Bq[8];
    int t = threadIdx.x;
    if (t < 4) { scal[8 + 2 * t] = 3.0e38f; scal[9 + 2 * t] = 0.0f; }
    if (t < 8) {
        float a = 0.f;
        for (int c = 0; c < 128; ++c) a += w1_q[t * 128 + c];
        float cv = 0.f, ci = 0.f;
        for (int c = 0; c < 64; ++c) { cv += w1_vi[t * 64 + c]; ci += w1_ir[t * 64 + c]; }
        Ad[t] = a; Cv[t] = cv; Ci[t] = ci; Bq[t] = b1_q[t];
    }
    __syncthreads();
    if (t == 0) {
        float av = 0, gv = 0, ai = 0, gi = 0;
        for (int d = 0; d < 8; ++d) {
            av += Ad[d] * Cv[d]; gv += Bq[d] * Cv[d];
            ai += Ad[d] * Ci[d]; gi += Bq[d] * Ci[d];
        }
        scal[0] = av; scal[1] = gv;   // alpha_vi, gamma_vi  (vi_attn)
        scal[2] = ai; scal[3] = gi;   // alpha_ir, gamma_ir  (ir_attn)
    }
}

// K1: per-(b,mod) channel sum s[n] = sum_c x[c,n]
__global__ void k1_chansum(const float* __restrict__ vi, const float* __restrict__ ir,
                           float* __restrict__ s) {
    int bm = blockIdx.y;                       // b*2+mod
    int n = blockIdx.x * 256 + threadIdx.x;
    const float* x = ((bm & 1) ? ir : vi) + (bm >> 1) * (64 * 4096) + n;
    float acc = 0.f;
    #pragma unroll 8
    for (int c = 0; c < 64; ++c) acc += x[c * 4096];
    s[bm * 4096 + n] = acc;
}

// K2: 3x3 sobel (zero pad) -> e_vi, e_ir, e_q; global min/max of e_vi/e_ir.
__global__ void k2_sobel(const float* __restrict__ s,
                         const float* __restrict__ wsx_vi, const float* __restrict__ wsy_vi,
                         const float* __restrict__ wsx_q, const float* __restrict__ wsy_q,
                         const float* __restrict__ wsx_ir, const float* __restrict__ wsy_ir,
                         float* __restrict__ e, float* __restrict__ scal) {
    int b = blockIdx.y;
    int n = blockIdx.x * 256 + threadIdx.x;
    int h = n >> 6, w = n & 63;
    const float* sv = s + (b * 2 + 0) * 4096;
    const float* si = s + (b * 2 + 1) * 4096;
    float nv[3][3], ni[3][3];
    #pragma unroll
    for (int i = 0; i < 3; ++i)
        #pragma unroll
        for (int j = 0; j < 3; ++j) {
            int hh = h + i - 1, ww = w + j - 1;
            bool in = (hh >= 0) & (hh < 64) & (ww >= 0) & (ww < 64);
            int idx = hh * 64 + ww;
            nv[i][j] = in ? sv[idx] : 0.f;
            ni[i][j] = in ? si[idx] : 0.f;
        }
    float gxv = 0, gyv = 0, gxi = 0, gyi = 0, gxq = 0, gyq = 0;
    #pragma unroll
    for (int i = 0; i < 3; ++i)
        #pragma unroll
        for (int j = 0; j < 3; ++j) {
            int k = i * 3 + j;
            gxv += nv[i][j] * wsx_vi[k]; gyv += nv[i][j] * wsy_vi[k];
            gxi += ni[i][j] * wsx_ir[k]; gyi += ni[i][j] * wsy_ir[k];
            float q = nv[i][j] + ni[i][j];
            gxq += q * wsx_q[k]; gyq += q * wsy_q[k];
        }
    float ev = fabsf(gxv) + fabsf(gyv);
    float ei = fabsf(gxi) + fabsf(gyi);
    float eq = fabsf(gxq) + fabsf(gyq);
    e[(b * 3 + 0) * 4096 + n] = ev;
    e[(b * 3 + 1) * 4096 + n] = ei;
    e[(b * 3 + 2) * 4096 + n] = eq;
    // wave-level min/max, one atomic per wave (e >= 0 so int-bit compare works)
    float mnv = ev, mxv = ev, mni = ei, mxi = ei;
    for (int o = 32; o; o >>= 1) {
        mnv = fminf(mnv, __shfl_down(mnv, o));
        mxv = fmaxf(mxv, __shfl_down(mxv, o));
        mni = fminf(mni, __shfl_down(mni, o));
        mxi = fmaxf(mxi, __shfl_down(mxi, o));
    }
    if ((threadIdx.x & 63) == 0) {
        int* sc = (int*)scal;
        atomicMin(&sc[8 + (b * 2 + 0) * 2], __float_as_int(mnv));
        atomicMax(&sc[9 + (b * 2 + 0) * 2], __float_as_int(mxv));
        atomicMin(&sc[8 + (b * 2 + 1) * 2], __float_as_int(mni));
        atomicMax(&sc[9 + (b * 2 + 1) * 2], __float_as_int(mxi));
    }
}

// K3: values 1x1 conv, output bf16 [b][mod][c][n]
__global__ void k3_values(const float* __restrict__ vi, const float* __restrict__ ir,
                          const float* __restrict__ wv_vi, const float* __restrict__ bv_vi,
                          const float* __restrict__ wv_ir, const float* __restrict__ bv_ir,
                          __hip_bfloat16* __restrict__ Vc) {
    __shared__ float wl[64 * 64];
    int bm = blockIdx.y; int b = bm >> 1, mod = bm & 1;
    const float* wv = mod ? wv_ir : wv_vi;
    const float* bv = mod ? bv_ir : bv_vi;
    const float* x = (mod ? ir : vi) + b * (64 * 4096);
    for (int i = threadIdx.x; i < 4096; i += 256) wl[i] = wv[i];
    __syncthreads();
    int nl = threadIdx.x & 63;
    int cq = threadIdx.x >> 6;                 // 0..3 -> 16 output channels each
    int n = blockIdx.x * 64 + nl;
    float xr[64];
    #pragma unroll 8
    for (int c2 = 0; c2 < 64; ++c2) xr[c2] = x[c2 * 4096 + n];
    __hip_bfloat16* out = Vc + (bm * 64) * 4096;
    for (int c = cq * 16; c < cq * 16 + 16; ++c) {
        float acc = bv[c];
        #pragma unroll 8
        for (int c2 = 0; c2 < 64; ++c2) acc += wl[c * 64 + c2] * xr[c2];
        out[c * 4096 + n] = __float2bfloat16(acc);
    }
}

// K4: main attention-weighted combine.
//   O[c,m] = sum_n V[c,n] * exp(t_m*e[n] - M_m),  Z[m] = sum_n exp(...)
// MFMA 16x16x32 bf16: A = V fragment (global, L2-hot), B = P computed in-reg.
__global__ __launch_bounds__(256) void k4_attn(
        const float* __restrict__ e, const float* __restrict__ scal,
        const __hip_bfloat16* __restrict__ Vc,
        float* __restrict__ Opart, float* __restrict__ Zpart,
        float* __restrict__ out, int S) {
    int mt = blockIdx.x;          // m-tile (64 rows)
    int bw = blockIdx.y;          // b*2+which
    int sp = blockIdx.z;          // K split
    int b = bw >> 1, which = bw & 1;
    int amod = which ? 0 : 1;     // which=0: vi_out uses ir_attn keys
    int vmod = which;             // which=0: V = vi values
    const float* e_att = e + (b * 3 + amod) * 4096;
    const float* e_q   = e + (b * 3 + 2) * 4096;
    float alpha = scal[which ? 0 : 2];
    float gamma = scal[which ? 1 : 3];
    float emn = scal[8 + (b * 2 + amod) * 2];
    float emx = scal[9 + (b * 2 + amod) * 2];
    const __hip_bfloat16* V = Vc + ((b * 2 + vmod) * 64) * 4096;

    int tid = threadIdx.x;
    int wv = tid >> 6, lane = tid & 63;
    int col = lane & 15, g = lane >> 4;
    int m = mt * 64 + wv * 16 + col;
    float t = alpha * e_q[m] + gamma;
    float M = (t > 0.f) ? t * emx : t * emn;   // exact global row max

    f32x4 acc[4] = {};
    float zacc = 0.f;
    int Klen = 4096 / S;
    int n_beg = sp * Klen;
    const float* ea = e_att + g * 8;
    const __hip_bfloat16* vrow = V + col * 4096 + g * 8;
    for (int n0 = n_beg; n0 < n_beg + Klen; n0 += 32) {
        f32x4 e0 = *(const f32x4*)(ea + n0);
        f32x4 e1 = *(const f32x4*)(ea + n0 + 4);
        float p[8];
        #pragma unroll
        for (int j = 0; j < 4; ++j) {
            p[j]     = __expf(t * e0[j] - M);
            p[4 + j] = __expf(t * e1[j] - M);
        }
        bf16x8 bfrag;
        #pragma unroll
        for (int j = 0; j < 8; ++j) {
            zacc += p[j];
            __hip_bfloat16 hb = __float2bfloat16(p[j]);
            short bits; __builtin_memcpy(&bits, &hb, 2);
            bfrag[j] = bits;
        }
        #pragma unroll
        for (int cb = 0; cb < 4; ++cb) {
            bf16x8 afrag = *(const bf16x8*)(vrow + cb * 16 * 4096 + n0);
            acc[cb] = __builtin_amdgcn_mfma_f32_16x16x32_bf16(afrag, bfrag, acc[cb], 0, 0, 0);
        }
    }
    // Z: sum the 4 k-groups that share this m (lanes l, l^16, l^32, l^48)
    zacc += __shfl_xor(zacc, 16);
    zacc += __shfl_xor(zacc, 32);

    if (S == 1) {
        float inv = 1.0f / zacc;
        float* o = out + which * (2 * 64 * 4096) + b * (64 * 4096) + m;
        #pragma unroll
        for (int cb = 0; cb < 4; ++cb) {
            int c = cb * 16 + g * 4;
            #pragma unroll
            for (int r = 0; r < 4; ++r) o[(c + r) * 4096] = acc[cb][r] * inv;
        }
    } else {
        float* op = Opart + (size_t)((bw * S + sp) * 64) * 4096 + m;
        #pragma unroll
        for (int cb = 0; cb < 4; ++cb) {
            int c = cb * 16 + g * 4;
            #pragma unroll
            for (int r = 0; r < 4; ++r) op[(c + r) * 4096] = acc[cb][r];
        }
        if (g == 0) Zpart[(bw * S + sp) * 4096 + m] = zacc;
    }
}

// K5: combine K-split partials and normalize.
__global__ void k5_combine(const float* __restrict__ Opart, const float* __restrict__ Zpart,
                           float* __restrict__ out, int S) {
    int bw = blockIdx.y; int b = bw >> 1, which = bw & 1;
    int cm = blockIdx.x * 256 + threadIdx.x;   // c*4096 + m
    int m = cm & 4095;
    float num = 0.f, den = 0.f;
    for (int sp = 0; sp < S; ++sp) {
        num += Opart[(size_t)((bw * S + sp) * 64) * 4096 + cm];
        den += Zpart[(bw * S + sp) * 4096 + m];
    }
    out[which * (2 * 64 * 4096) + b * (64 * 4096) + cm] = num / den;
}

extern "C" void kernel_launch(void* const* d_in, const int* in_sizes, int n_in,
                              void* d_out, int out_size, void* d_ws, size_t ws_size,
                              hipStream_t stream) {
    const float* vi     = (const float*)d_in[0];
    const float* ir     = (const float*)d_in[1];
    const float* wsx_vi = (const float*)d_in[2];
    const float* wsy_vi = (const float*)d_in[3];
    const float* w1_vi  = (const float*)d_in[4];
    const float* b1_vi  = (const float*)d_in[5];
    const float* wsx_q  = (const float*)d_in[6];
    const float* wsy_q  = (const float*)d_in[7];
    const float* w1_q   = (const float*)d_in[8];
    const float* b1_q   = (const float*)d_in[9];
    const float* wsx_ir = (const float*)d_in[10];
    const float* wsy_ir = (const float*)d_in[11];
    const float* w1_ir  = (const float*)d_in[12];
    const float* b1_ir  = (const float*)d_in[13];
    const float* wv_vi  = (const float*)d_in[14];
    const float* bv_vi  = (const float*)d_in[15];
    const float* wv_ir  = (const float*)d_in[16];
    const float* bv_ir  = (const float*)d_in[17];
    (void)in_sizes; (void)n_in; (void)out_size; (void)b1_vi; (void)b1_ir;

    char* ws = (char*)d_ws;
    float* scal = (float*)ws;                              // 256 B
    float* s    = (float*)(ws + 256);                      // 128 KB
    float* e    = (float*)(ws + 256 + 131072);             // 96 KB
    __hip_bfloat16* Vc = (__hip_bfloat16*)(ws + 229632);   // 2 MB
    int S = 4;
    size_t need = 2326784 + (size_t)S * 4194304 + (size_t)S * 65536;
    if (ws_size < need) S = 1;
    float* Opart = (float*)(ws + 2326784);
    float* Zpart = (float*)(ws + 2326784 + (size_t)S * 4194304);
    float* out = (float*)d_out;

    k0_scalars<<<1, 64, 0, stream>>>(w1_vi, b1_vi, w1_q, b1_q, w1_ir, b1_ir, scal);
    k1_chansum<<<dim3(16, 4), 256, 0, stream>>>(vi, ir, s);
    k2_sobel<<<dim3(16, 2), 256, 0, stream>>>(s, wsx_vi, wsy_vi, wsx_q, wsy_q,
                                              wsx_ir, wsy_ir, e, scal);
    k3_values<<<dim3(64, 4), 256, 0, stream>>>(vi, ir, wv_vi, bv_vi, wv_ir, bv_ir, Vc);
    k4_attn<<<dim3(64, 4, S), 256, 0, stream>>>(e, scal, Vc, Opart, Zpart, out, S);
    if (S > 1) k5_combine<<<dim3(1024, 4), 256, 0, stream>>>(Opart, Zpart, out, S);
}

// Round 2
// 132.249 us; speedup vs baseline: 1.0008x; 1.0008x over previous
//
#include <hip/hip_runtime.h>
#include <hip/hip_bf16.h>

typedef __attribute__((ext_vector_type(8))) short bf16x8;
typedef __attribute__((ext_vector_type(4))) float f32x4;
typedef __attribute__((ext_vector_type(4))) int   i32x4;

// ---------------------------------------------------------------------------
// B=2, C=64, H=W=64, N=4096, dk=8.
// Sobel weights are broadcast over [C,C,3,3] -> conv output = conv(chansum).
// Keys/queries affine in scalar field e[n]; softmax row m = softmax_n(t_m*e[n]),
// t_m = alpha*eq[m]+gamma; row max = t*e_max (t>0) else t*e_min -> K-split
// partials add with a COMMON max (no flash rescale needed).
// scal layout: [0..3] alpha_vi,gamma_vi,alpha_ir,gamma_ir;
//              float[8..11] = min e (bm), float[12..15] = max e (bm)
// ---------------------------------------------------------------------------

// kA: fused chansum (2-row tile + 1-row halo, recomputed) -> sobel -> e fields,
//     global min/max atomics, and (block 0,0) the alpha/gamma scalar reduction.
__global__ __launch_bounds__(256) void kA_prep(
    const float* __restrict__ vi, const float* __restrict__ ir,
    const float* __restrict__ wsx_vi, const float* __restrict__ wsy_vi,
    const float* __restrict__ wsx_q,  const float* __restrict__ wsy_q,
    const float* __restrict__ wsx_ir, const float* __restrict__ wsy_ir,
    const float* __restrict__ w1_vi, const float* __restrict__ w1_q,
    const float* __restrict__ b1_q,  const float* __restrict__ w1_ir,
    float* __restrict__ e, float* __restrict__ scal) {
    __shared__ float sv[256], si[256];           // 4 rows x 64 cols per mod
    __shared__ float Ad[8], Cv[8], Ci[8], Bq[8];
    const int b = blockIdx.y, rt = blockIdx.x, t = threadIdx.x;
    const int r0 = rt * 2;
    const float* xv = vi + b * 64 * 4096;
    const float* xi = ir + b * 64 * 4096;
    if (b == 0 && rt == 0 && t < 8) {
        float a = 0.f;
        for (int c = 0; c < 128; ++c) a += w1_q[t * 128 + c];
        float cv = 0.f, ci = 0.f;
        for (int c = 0; c < 64; ++c) { cv += w1_vi[t * 64 + c]; ci += w1_ir[t * 64 + c]; }
        Ad[t] = a; Cv[t] = cv; Ci[t] = ci; Bq[t] = b1_q[t];
    }
    // 512 chansum tasks (4 rows x 64 cols x 2 mods), 2 per thread
    #pragma unroll
    for (int k = 0; k < 2; ++k) {
        int id = t + k * 256;
        int mod = id >> 8;
        int entry = id & 255;
        int grow = r0 - 1 + (entry >> 6);
        int col = entry & 63;
        float acc = 0.f;
        if (grow >= 0 && grow < 64) {
            const float* x = (mod ? xi : xv) + grow * 64 + col;
            #pragma unroll 16
            for (int c = 0; c < 64; ++c) acc += x[c * 4096];
        }
        (mod ? si : sv)[entry] = acc;
    }
    __syncthreads();
    if (b == 0 && rt == 0 && t == 0) {
        float av = 0, gv = 0, ai = 0, gi = 0;
        for (int d = 0; d < 8; ++d) {
            av += Ad[d] * Cv[d]; gv += Bq[d] * Cv[d];
            ai += Ad[d] * Ci[d]; gi += Bq[d] * Ci[d];
        }
        scal[0] = av; scal[1] = gv; scal[2] = ai; scal[3] = gi;
    }
    if (t < 128) {                                // 2 rows x 64 cols outputs
        int row = t >> 6, col = t & 63;
        int n = (r0 + row) * 64 + col;
        float nv[3][3], ni[3][3];
        #pragma unroll
        for (int di = 0; di < 3; ++di)
            #pragma unroll
            for (int dj = 0; dj < 3; ++dj) {
                int cc = col + dj - 1;
                bool in = (cc >= 0) & (cc < 64);
                int idx = (row + di) * 64 + (in ? cc : 0);
                nv[di][dj] = in ? sv[idx] : 0.f;
                ni[di][dj] = in ? si[idx] : 0.f;
            }
        float gxv = 0, gyv = 0, gxi = 0, gyi = 0, gxq = 0, gyq = 0;
        #pragma unroll
        for (int i = 0; i < 3; ++i)
            #pragma unroll
            for (int j = 0; j < 3; ++j) {
                int k = i * 3 + j;
                gxv += nv[i][j] * wsx_vi[k]; gyv += nv[i][j] * wsy_vi[k];
                gxi += ni[i][j] * wsx_ir[k]; gyi += ni[i][j] * wsy_ir[k];
                float q = nv[i][j] + ni[i][j];
                gxq += q * wsx_q[k]; gyq += q * wsy_q[k];
            }
        float ev = fabsf(gxv) + fabsf(gyv);
        float ei = fabsf(gxi) + fabsf(gyi);
        float eq = fabsf(gxq) + fabsf(gyq);
        e[(b * 3 + 0) * 4096 + n] = ev;
        e[(b * 3 + 1) * 4096 + n] = ei;
        e[(b * 3 + 2) * 4096 + n] = eq;
        float mnv = ev, mxv = ev, mni = ei, mxi = ei;
        for (int o = 32; o; o >>= 1) {
            mnv = fminf(mnv, __shfl_down(mnv, o));
            mxv = fmaxf(mxv, __shfl_down(mxv, o));
            mni = fminf(mni, __shfl_down(mni, o));
            mxi = fmaxf(mxi, __shfl_down(mxi, o));
        }
        if ((t & 63) == 0) {
            int* sc = (int*)scal;
            atomicMin(&sc[8  + b * 2 + 0], __float_as_int(mnv));
            atomicMax(&sc[12 + b * 2 + 0], __float_as_int(mxv));
            atomicMin(&sc[8  + b * 2 + 1], __float_as_int(mni));
            atomicMax(&sc[12 + b * 2 + 1], __float_as_int(mxi));
        }
    }
}

// k3: values 1x1 conv, output bf16 [b][mod][c][n]
__global__ void k3_values(const float* __restrict__ vi, const float* __restrict__ ir,
                          const float* __restrict__ wv_vi, const float* __restrict__ bv_vi,
                          const float* __restrict__ wv_ir, const float* __restrict__ bv_ir,
                          __hip_bfloat16* __restrict__ Vc) {
    __shared__ float wl[64 * 64];
    int bm = blockIdx.y; int b = bm >> 1, mod = bm & 1;
    const float* wv = mod ? wv_ir : wv_vi;
    const float* bv = mod ? bv_ir : bv_vi;
    const float* x = (mod ? ir : vi) + b * (64 * 4096);
    for (int i = threadIdx.x; i < 4096; i += 256) wl[i] = wv[i];
    __syncthreads();
    int nl = threadIdx.x & 63;
    int cq = threadIdx.x >> 6;
    int n = blockIdx.x * 64 + nl;
    float xr[64];
    #pragma unroll 8
    for (int c2 = 0; c2 < 64; ++c2) xr[c2] = x[c2 * 4096 + n];
    __hip_bfloat16* out = Vc + (bm * 64) * 4096;
    for (int c = cq * 16; c < cq * 16 + 16; ++c) {
        float acc = bv[c];
        #pragma unroll 8
        for (int c2 = 0; c2 < 64; ++c2) acc += wl[c * 64 + c2] * xr[c2];
        out[c * 4096 + n] = __float2bfloat16(acc);
    }
}

// k4: O[c,m] = sum_n V[c,n] * 2^(t2_m*e[n] - M2_m);  Z via ones-MFMA.
// Software-pipelined: prefetch next chunk's V-frags + e while computing.
__global__ __launch_bounds__(256, 4) void k4_attn(
        const float* __restrict__ e, const float* __restrict__ scal,
        const __hip_bfloat16* __restrict__ Vc,
        float* __restrict__ Opart, float* __restrict__ Zpart,
        float* __restrict__ out, int S) {
    const int mt = blockIdx.x, bw = blockIdx.y, sp = blockIdx.z;
    const int b = bw >> 1, which = bw & 1;
    const int amod = which ? 0 : 1;
    const int vmod = which;
    const float* e_att = e + (b * 3 + amod) * 4096;
    const float* e_q   = e + (b * 3 + 2) * 4096;
    const float alpha = scal[which ? 0 : 2];
    const float gamma = scal[which ? 1 : 3];
    const float emn = scal[8  + b * 2 + amod];
    const float emx = scal[12 + b * 2 + amod];
    const __hip_bfloat16* V = Vc + (size_t)((b * 2 + vmod) * 64) * 4096;

    const int tid = threadIdx.x;
    const int wv = tid >> 6, lane = tid & 63;
    const int col = lane & 15, g = lane >> 4;
    const int m = mt * 64 + wv * 16 + col;
    const float L2E = 1.4426950408889634f;
    const float t  = alpha * e_q[m] + gamma;
    const float t2 = t * L2E;
    const float nM2 = -((t > 0.f) ? t * emx : t * emn) * L2E;

    f32x4 acc[4] = {};
    f32x4 accz = {};
    bf16x8 ones;
    #pragma unroll
    for (int j = 0; j < 8; ++j) ones[j] = (short)0x3F80;   // bf16 1.0

    const int Klen = 4096 / S, n_beg = sp * Klen, iters = Klen / 32;
    const float* ea = e_att + g * 8;
    const __hip_bfloat16* vrow = V + col * 4096 + g * 8;

    // prologue prefetch
    f32x4 ec0 = *(const f32x4*)(ea + n_beg);
    f32x4 ec1 = *(const f32x4*)(ea + n_beg + 4);
    bf16x8 acur[4];
    #pragma unroll
    for (int cb = 0; cb < 4; ++cb)
        acur[cb] = *(const bf16x8*)(vrow + cb * 16 * 4096 + n_beg);

    for (int it = 0; it < iters; ++it) {
        const int nn = n_beg + ((it + 1 < iters) ? (it + 1) * 32 : 0);
        // issue next-chunk loads first (independent of current compute)
        f32x4 f0 = *(const f32x4*)(ea + nn);
        f32x4 f1 = *(const f32x4*)(ea + nn + 4);
        bf16x8 anxt[4];
        #pragma unroll
        for (int cb = 0; cb < 4; ++cb)
            anxt[cb] = *(const bf16x8*)(vrow + cb * 16 * 4096 + nn);

        float p[8];
        #pragma unroll
        for (int j = 0; j < 4; ++j) {
            float g0 = fmaf(ec0[j], t2, nM2);
            float g1 = fmaf(ec1[j], t2, nM2);
            asm("v_exp_f32 %0, %1" : "=v"(p[j])     : "v"(g0));
            asm("v_exp_f32 %0, %1" : "=v"(p[j + 4]) : "v"(g1));
        }
        int pk0, pk1, pk2, pk3;
        asm("v_cvt_pk_bf16_f32 %0, %1, %2" : "=v"(pk0) : "v"(p[0]), "v"(p[1]));
        asm("v_cvt_pk_bf16_f32 %0, %1, %2" : "=v"(pk1) : "v"(p[2]), "v"(p[3]));
        asm("v_cvt_pk_bf16_f32 %0, %1, %2" : "=v"(pk2) : "v"(p[4]), "v"(p[5]));
        asm("v_cvt_pk_bf16_f32 %0, %1, %2" : "=v"(pk3) : "v"(p[6]), "v"(p[7]));
        i32x4 pki = {pk0, pk1, pk2, pk3};
        bf16x8 bfrag = __builtin_bit_cast(bf16x8, pki);

        #pragma unroll
        for (int cb = 0; cb < 4; ++cb)
            acc[cb] = __builtin_amdgcn_mfma_f32_16x16x32_bf16(acur[cb], bfrag, acc[cb], 0, 0, 0);
        accz = __builtin_amdgcn_mfma_f32_16x16x32_bf16(ones, bfrag, accz, 0, 0, 0);

        #pragma unroll
        for (int cb = 0; cb < 4; ++cb) acur[cb] = anxt[cb];
        ec0 = f0; ec1 = f1;
    }
    const float Z = accz[0];   // ones-A => every row/reg holds full chunk-sum

    if (S == 1) {
        float inv = 1.0f / Z;
        float* o = out + which * (2 * 64 * 4096) + b * (64 * 4096) + m;
        #pragma unroll
        for (int cb = 0; cb < 4; ++cb) {
            int c = cb * 16 + g * 4;
            #pragma unroll
            for (int r = 0; r < 4; ++r) o[(c + r) * 4096] = acc[cb][r] * inv;
        }
    } else {
        float* op = Opart + (size_t)((bw * S + sp) * 64) * 4096 + m;
        #pragma unroll
        for (int cb = 0; cb < 4; ++cb) {
            int c = cb * 16 + g * 4;
            #pragma unroll
            for (int r = 0; r < 4; ++r) op[(c + r) * 4096] = acc[cb][r];
        }
        if (lane < 16) Zpart[(bw * S + sp) * 4096 + m] = Z;
    }
}

// k5: combine K-split partials and normalize (vectorized).
__global__ __launch_bounds__(256) void k5_combine(
        const float* __restrict__ Opart, const float* __restrict__ Zpart,
        float* __restrict__ out, int S) {
    int bw = blockIdx.y; int b = bw >> 1, which = bw & 1;
    int idx = (blockIdx.x * 256 + threadIdx.x) * 4;   // over 64*4096
    int m = idx & 4095;
    f32x4 num = {}; f32x4 den = {};
    for (int sp = 0; sp < S; ++sp) {
        num += *(const f32x4*)(Opart + (size_t)((bw * S + sp) * 64) * 4096 + idx);
        den += *(const f32x4*)(Zpart + (bw * S + sp) * 4096 + m);
    }
    *(f32x4*)(out + which * (2 * 64 * 4096) + b * (64 * 4096) + idx) = num / den;
}

extern "C" void kernel_launch(void* const* d_in, const int* in_sizes, int n_in,
                              void* d_out, int out_size, void* d_ws, size_t ws_size,
                              hipStream_t stream) {
    const float* vi     = (const float*)d_in[0];
    const float* ir     = (const float*)d_in[1];
    const float* wsx_vi = (const float*)d_in[2];
    const float* wsy_vi = (const float*)d_in[3];
    const float* w1_vi  = (const float*)d_in[4];
    const float* wsx_q  = (const float*)d_in[6];
    const float* wsy_q  = (const float*)d_in[7];
    const float* w1_q   = (const float*)d_in[8];
    const float* b1_q   = (const float*)d_in[9];
    const float* wsx_ir = (const float*)d_in[10];
    const float* wsy_ir = (const float*)d_in[11];
    const float* w1_ir  = (const float*)d_in[12];
    const float* wv_vi  = (const float*)d_in[14];
    const float* bv_vi  = (const float*)d_in[15];
    const float* wv_ir  = (const float*)d_in[16];
    const float* bv_ir  = (const float*)d_in[17];
    (void)in_sizes; (void)n_in; (void)out_size;

    char* ws = (char*)d_ws;
    float* scal = (float*)ws;                              // 256 B
    float* e    = (float*)(ws + 256);                      // 6*4096*4 = 96 KB
    __hip_bfloat16* Vc = (__hip_bfloat16*)(ws + 98560);    // 2 MB
    int S = 4;
    size_t need = 2195712 + (size_t)S * (4194304 + 65536);
    if (ws_size < need) S = 1;
    float* Opart = (float*)(ws + 2195712);
    float* Zpart = (float*)(ws + 2195712 + (size_t)S * 4194304);
    float* out = (float*)d_out;

    // init min slots to +big (0x7f7f7f7f ~ 3.4e38), max slots to 0
    hipMemsetAsync(ws + 32, 0x7F, 16, stream);
    hipMemsetAsync(ws + 48, 0x00, 16, stream);

    kA_prep<<<dim3(32, 2), 256, 0, stream>>>(vi, ir, wsx_vi, wsy_vi, wsx_q, wsy_q,
                                             wsx_ir, wsy_ir, w1_vi, w1_q, b1_q, w1_ir,
                                             e, scal);
    k3_values<<<dim3(64, 4), 256, 0, stream>>>(vi, ir, wv_vi, bv_vi, wv_ir, bv_ir, Vc);
    k4_attn<<<dim3(64, 4, S), 256, 0, stream>>>(e, scal, Vc, Opart, Zpart, out, S);
    if (S > 1) k5_combine<<<dim3(256, 4), 256, 0, stream>>>(Opart, Zpart, out, S);
}

// Round 3
// 92.136 us; speedup vs baseline: 1.4365x; 1.4354x over previous
//
#include <hip/hip_runtime.h>
#include <hip/hip_bf16.h>

typedef __attribute__((ext_vector_type(8))) short bf16x8;
typedef __attribute__((ext_vector_type(4))) float f32x4;
typedef __attribute__((ext_vector_type(4))) int   i32x4;

// ---------------------------------------------------------------------------
// B=2, C=64, H=W=64, N=4096, dk=8.
// Sobel weights are broadcast over [C,C,3,3] -> conv output = conv(chansum).
// Keys/queries affine in scalar field e[n]; softmax row m = softmax_n(t_m*e[n]),
// t_m = alpha*eq[m]+gamma; row max = t*e_max (t>0) else t*e_min -> K-split
// partials add with a COMMON max (no flash rescale needed).
// scal layout: [0..3] alpha_vi,gamma_vi,alpha_ir,gamma_ir;
//              float[8..11] = min e (bm), float[12..15] = max e (bm)
// ---------------------------------------------------------------------------

// kA: fused chansum (2-row tile + 1-row halo, recomputed) -> sobel -> e fields,
//     global min/max atomics, and (block 0,0) the alpha/gamma scalar reduction.
__global__ __launch_bounds__(256) void kA_prep(
    const float* __restrict__ vi, const float* __restrict__ ir,
    const float* __restrict__ wsx_vi, const float* __restrict__ wsy_vi,
    const float* __restrict__ wsx_q,  const float* __restrict__ wsy_q,
    const float* __restrict__ wsx_ir, const float* __restrict__ wsy_ir,
    const float* __restrict__ w1_vi, const float* __restrict__ w1_q,
    const float* __restrict__ b1_q,  const float* __restrict__ w1_ir,
    float* __restrict__ e, float* __restrict__ scal) {
    __shared__ float sv[256], si[256];           // 4 rows x 64 cols per mod
    __shared__ float Ad[8], Cv[8], Ci[8], Bq[8];
    const int b = blockIdx.y, rt = blockIdx.x, t = threadIdx.x;
    const int r0 = rt * 2;
    const float* xv = vi + b * 64 * 4096;
    const float* xi = ir + b * 64 * 4096;
    if (b == 0 && rt == 0 && t < 8) {
        float a = 0.f;
        for (int c = 0; c < 128; ++c) a += w1_q[t * 128 + c];
        float cv = 0.f, ci = 0.f;
        for (int c = 0; c < 64; ++c) { cv += w1_vi[t * 64 + c]; ci += w1_ir[t * 64 + c]; }
        Ad[t] = a; Cv[t] = cv; Ci[t] = ci; Bq[t] = b1_q[t];
    }
    #pragma unroll
    for (int k = 0; k < 2; ++k) {
        int id = t + k * 256;
        int mod = id >> 8;
        int entry = id & 255;
        int grow = r0 - 1 + (entry >> 6);
        int col = entry & 63;
        float acc = 0.f;
        if (grow >= 0 && grow < 64) {
            const float* x = (mod ? xi : xv) + grow * 64 + col;
            #pragma unroll 16
            for (int c = 0; c < 64; ++c) acc += x[c * 4096];
        }
        (mod ? si : sv)[entry] = acc;
    }
    __syncthreads();
    if (b == 0 && rt == 0 && t == 0) {
        float av = 0, gv = 0, ai = 0, gi = 0;
        for (int d = 0; d < 8; ++d) {
            av += Ad[d] * Cv[d]; gv += Bq[d] * Cv[d];
            ai += Ad[d] * Ci[d]; gi += Bq[d] * Ci[d];
        }
        scal[0] = av; scal[1] = gv; scal[2] = ai; scal[3] = gi;
    }
    if (t < 128) {
        int row = t >> 6, col = t & 63;
        int n = (r0 + row) * 64 + col;
        float nv[3][3], ni[3][3];
        #pragma unroll
        for (int di = 0; di < 3; ++di)
            #pragma unroll
            for (int dj = 0; dj < 3; ++dj) {
                int cc = col + dj - 1;
                bool in = (cc >= 0) & (cc < 64);
                int idx = (row + di) * 64 + (in ? cc : 0);
                nv[di][dj] = in ? sv[idx] : 0.f;
                ni[di][dj] = in ? si[idx] : 0.f;
            }
        float gxv = 0, gyv = 0, gxi = 0, gyi = 0, gxq = 0, gyq = 0;
        #pragma unroll
        for (int i = 0; i < 3; ++i)
            #pragma unroll
            for (int j = 0; j < 3; ++j) {
                int k = i * 3 + j;
                gxv += nv[i][j] * wsx_vi[k]; gyv += nv[i][j] * wsy_vi[k];
                gxi += ni[i][j] * wsx_ir[k]; gyi += ni[i][j] * wsy_ir[k];
                float q = nv[i][j] + ni[i][j];
                gxq += q * wsx_q[k]; gyq += q * wsy_q[k];
            }
        float ev = fabsf(gxv) + fabsf(gyv);
        float ei = fabsf(gxi) + fabsf(gyi);
        float eq = fabsf(gxq) + fabsf(gyq);
        e[(b * 3 + 0) * 4096 + n] = ev;
        e[(b * 3 + 1) * 4096 + n] = ei;
        e[(b * 3 + 2) * 4096 + n] = eq;
        float mnv = ev, mxv = ev, mni = ei, mxi = ei;
        for (int o = 32; o; o >>= 1) {
            mnv = fminf(mnv, __shfl_down(mnv, o));
            mxv = fmaxf(mxv, __shfl_down(mxv, o));
            mni = fminf(mni, __shfl_down(mni, o));
            mxi = fmaxf(mxi, __shfl_down(mxi, o));
        }
        if ((t & 63) == 0) {
            int* sc = (int*)scal;
            atomicMin(&sc[8  + b * 2 + 0], __float_as_int(mnv));
            atomicMax(&sc[12 + b * 2 + 0], __float_as_int(mxv));
            atomicMin(&sc[8  + b * 2 + 1], __float_as_int(mni));
            atomicMax(&sc[12 + b * 2 + 1], __float_as_int(mxi));
        }
    }
}

// k3: values 1x1 conv, output bf16 [b][mod][c][n]
__global__ void k3_values(const float* __restrict__ vi, const float* __restrict__ ir,
                          const float* __restrict__ wv_vi, const float* __restrict__ bv_vi,
                          const float* __restrict__ wv_ir, const float* __restrict__ bv_ir,
                          __hip_bfloat16* __restrict__ Vc) {
    __shared__ float wl[64 * 64];
    int bm = blockIdx.y; int b = bm >> 1, mod = bm & 1;
    const float* wv = mod ? wv_ir : wv_vi;
    const float* bv = mod ? bv_ir : bv_vi;
    const float* x = (mod ? ir : vi) + b * (64 * 4096);
    for (int i = threadIdx.x; i < 4096; i += 256) wl[i] = wv[i];
    __syncthreads();
    int nl = threadIdx.x & 63;
    int cq = threadIdx.x >> 6;
    int n = blockIdx.x * 64 + nl;
    float xr[64];
    #pragma unroll 8
    for (int c2 = 0; c2 < 64; ++c2) xr[c2] = x[c2 * 4096 + n];
    __hip_bfloat16* out = Vc + (bm * 64) * 4096;
    for (int c = cq * 16; c < cq * 16 + 16; ++c) {
        float acc = bv[c];
        #pragma unroll 8
        for (int c2 = 0; c2 < 64; ++c2) acc += wl[c * 64 + c2] * xr[c2];
        out[c * 4096 + n] = __float2bfloat16(acc);
    }
}

// k4: O[c,m] = sum_n V[c,n] * 2^(t2_m*e[n] - M2_m);  Z via ones-MFMA.
// V K-chunk (64x1024 bf16, 128KB) + e chunk staged in LDS once (coalesced,
// XOR-swizzled rows); inner loop is LDS + VALU + MFMA only. Each block
// covers MT=4 m-tiles so V fragments are reused 4x per LDS read.
#define KLEN 1024
#define MT 4
__global__ __launch_bounds__(256, 1) void k4_attn(
        const float* __restrict__ e, const float* __restrict__ scal,
        const __hip_bfloat16* __restrict__ Vc,
        float* __restrict__ Opart, float* __restrict__ Zpart) {
    __shared__ __align__(16) char vbuf[64 * KLEN * 2];   // 128 KB swizzled
    __shared__ __align__(16) float elds[KLEN];           // 4 KB
    const int mt8 = blockIdx.x;   // 16 groups of 256 m
    const int bw  = blockIdx.y;   // b*2+which
    const int sp  = blockIdx.z;   // 4 K-splits
    const int b = bw >> 1, which = bw & 1;
    const int amod = which ? 0 : 1;
    const int vmod = which;
    const float* e_att = e + (b * 3 + amod) * 4096;
    const float* e_q   = e + (b * 3 + 2) * 4096;
    const float alpha = scal[which ? 0 : 2];
    const float gamma = scal[which ? 1 : 3];
    const float emn = scal[8  + b * 2 + amod];
    const float emx = scal[12 + b * 2 + amod];
    const short* Vg = (const short*)(Vc + (size_t)((b * 2 + vmod) * 64) * 4096);

    const int tid = threadIdx.x;
    // -------- stage V[64][KLEN] (swizzled) + e[KLEN] into LDS --------
    #pragma unroll
    for (int k = 0; k < 32; ++k) {                 // 8192 16B-chunks / 256 thr
        int id = tid + k * 256;
        int c = id >> 7, s = id & 127;             // row c, 16B slot s
        bf16x8 v = *(const bf16x8*)(Vg + c * 4096 + sp * KLEN + s * 8);
        int dst = c * 2048 + ((s * 16) ^ ((c & 31) << 4));
        *(bf16x8*)(vbuf + dst) = v;
    }
    {
        f32x4 ev = *(const f32x4*)(e_att + sp * KLEN + tid * 4);
        *(f32x4*)(elds + tid * 4) = ev;
    }
    __syncthreads();

    const int wv = tid >> 6, lane = tid & 63;
    const int col = lane & 15, g = lane >> 4;
    const float L2E = 1.4426950408889634f;
    float t2[MT], nM2[MT];
    int mbase[MT];
    #pragma unroll
    for (int mt = 0; mt < MT; ++mt) {
        int m = mt8 * 256 + mt * 64 + wv * 16 + col;
        mbase[mt] = m;
        float t = alpha * e_q[m] + gamma;
        t2[mt]  = t * L2E;
        nM2[mt] = -((t > 0.f) ? t * emx : t * emn) * L2E;
    }

    f32x4 acc[MT][4] = {};
    f32x4 accz[MT] = {};
    bf16x8 ones;
    #pragma unroll
    for (int j = 0; j < 8; ++j) ones[j] = (short)0x3F80;

    for (int it = 0; it < KLEN / 32; ++it) {
        const int n0 = it * 32;
        bf16x8 af[4];
        #pragma unroll
        for (int cb = 0; cb < 4; ++cb) {
            int row = cb * 16 + col;
            int byte = row * 2048 + (((n0 + g * 8) * 2) ^ ((row & 31) << 4));
            af[cb] = *(const bf16x8*)(vbuf + byte);
        }
        f32x4 e0 = *(const f32x4*)(elds + n0 + g * 8);
        f32x4 e1 = *(const f32x4*)(elds + n0 + g * 8 + 4);
        #pragma unroll
        for (int mt = 0; mt < MT; ++mt) {
            float p[8];
            #pragma unroll
            for (int j = 0; j < 4; ++j) {
                float g0 = fmaf(e0[j], t2[mt], nM2[mt]);
                float g1 = fmaf(e1[j], t2[mt], nM2[mt]);
                asm("v_exp_f32 %0, %1" : "=v"(p[j])     : "v"(g0));
                asm("v_exp_f32 %0, %1" : "=v"(p[j + 4]) : "v"(g1));
            }
            int pk0, pk1, pk2, pk3;
            asm("v_cvt_pk_bf16_f32 %0, %1, %2" : "=v"(pk0) : "v"(p[0]), "v"(p[1]));
            asm("v_cvt_pk_bf16_f32 %0, %1, %2" : "=v"(pk1) : "v"(p[2]), "v"(p[3]));
            asm("v_cvt_pk_bf16_f32 %0, %1, %2" : "=v"(pk2) : "v"(p[4]), "v"(p[5]));
            asm("v_cvt_pk_bf16_f32 %0, %1, %2" : "=v"(pk3) : "v"(p[6]), "v"(p[7]));
            i32x4 pki = {pk0, pk1, pk2, pk3};
            bf16x8 bfrag = __builtin_bit_cast(bf16x8, pki);
            #pragma unroll
            for (int cb = 0; cb < 4; ++cb)
                acc[mt][cb] = __builtin_amdgcn_mfma_f32_16x16x32_bf16(af[cb], bfrag, acc[mt][cb], 0, 0, 0);
            accz[mt] = __builtin_amdgcn_mfma_f32_16x16x32_bf16(ones, bfrag, accz[mt], 0, 0, 0);
        }
    }

    float* opb = Opart + (size_t)((bw * 4 + sp) * 64) * 4096;
    #pragma unroll
    for (int mt = 0; mt < MT; ++mt) {
        float* op = opb + mbase[mt];
        #pragma unroll
        for (int cb = 0; cb < 4; ++cb) {
            int c = cb * 16 + g * 4;
            #pragma unroll
            for (int r = 0; r < 4; ++r) op[(c + r) * 4096] = acc[mt][cb][r];
        }
        if (lane < 16) Zpart[(bw * 4 + sp) * 4096 + mbase[mt]] = accz[mt][0];
    }
}

// k5: combine K-split partials and normalize (vectorized, S=4).
__global__ __launch_bounds__(256) void k5_combine(
        const float* __restrict__ Opart, const float* __restrict__ Zpart,
        float* __restrict__ out) {
    int bw = blockIdx.y; int b = bw >> 1, which = bw & 1;
    int idx = (blockIdx.x * 256 + threadIdx.x) * 4;
    int m = idx & 4095;
    f32x4 num = {}; f32x4 den = {};
    #pragma unroll
    for (int sp = 0; sp < 4; ++sp) {
        num += *(const f32x4*)(Opart + (size_t)((bw * 4 + sp) * 64) * 4096 + idx);
        den += *(const f32x4*)(Zpart + (bw * 4 + sp) * 4096 + m);
    }
    *(f32x4*)(out + which * (2 * 64 * 4096) + b * (64 * 4096) + idx) = num / den;
}

extern "C" void kernel_launch(void* const* d_in, const int* in_sizes, int n_in,
                              void* d_out, int out_size, void* d_ws, size_t ws_size,
                              hipStream_t stream) {
    const float* vi     = (const float*)d_in[0];
    const float* ir     = (const float*)d_in[1];
    const float* wsx_vi = (const float*)d_in[2];
    const float* wsy_vi = (const float*)d_in[3];
    const float* w1_vi  = (const float*)d_in[4];
    const float* wsx_q  = (const float*)d_in[6];
    const float* wsy_q  = (const float*)d_in[7];
    const float* w1_q   = (const float*)d_in[8];
    const float* b1_q   = (const float*)d_in[9];
    const float* wsx_ir = (const float*)d_in[10];
    const float* wsy_ir = (const float*)d_in[11];
    const float* w1_ir  = (const float*)d_in[12];
    const float* wv_vi  = (const float*)d_in[14];
    const float* bv_vi  = (const float*)d_in[15];
    const float* wv_ir  = (const float*)d_in[16];
    const float* bv_ir  = (const float*)d_in[17];
    (void)in_sizes; (void)n_in; (void)out_size;

    char* ws = (char*)d_ws;
    float* scal = (float*)ws;                              // 256 B
    float* e    = (float*)(ws + 256);                      // 96 KB
    __hip_bfloat16* Vc = (__hip_bfloat16*)(ws + 98560);    // 2 MB
    float* Opart = (float*)(ws + 2195712);                 // 16 MB (S=4)
    float* Zpart = (float*)(ws + 2195712 + 4ull * 4194304);
    float* out = (float*)d_out;
    (void)ws_size;

    hipMemsetAsync(ws + 32, 0x7F, 16, stream);   // min slots -> +big
    hipMemsetAsync(ws + 48, 0x00, 16, stream);   // max slots -> 0

    kA_prep<<<dim3(32, 2), 256, 0, stream>>>(vi, ir, wsx_vi, wsy_vi, wsx_q, wsy_q,
                                             wsx_ir, wsy_ir, w1_vi, w1_q, b1_q, w1_ir,
                                             e, scal);
    k3_values<<<dim3(64, 4), 256, 0, stream>>>(vi, ir, wv_vi, bv_vi, wv_ir, bv_ir, Vc);
    k4_attn<<<dim3(16, 4, 4), 256, 0, stream>>>(e, scal, Vc, Opart, Zpart);
    k5_combine<<<dim3(256, 4), 256, 0, stream>>>(Opart, Zpart, out);
}

// Round 4
// 59.538 us; speedup vs baseline: 2.2231x; 1.5475x over previous
//
#include <hip/hip_runtime.h>
#include <hip/hip_bf16.h>

typedef __attribute__((ext_vector_type(8))) short bf16x8;
typedef __attribute__((ext_vector_type(4))) float f32x4;
typedef __attribute__((ext_vector_type(4))) int   i32x4;

// ---------------------------------------------------------------------------
// B=2, C=64, H=W=64, N=4096, dk=8.
// Sobel weights are broadcast over [C,C,3,3] -> conv output = conv(chansum).
// Keys/queries affine in scalar field e[n]; softmax row m = softmax_n(t_m*e[n]),
// t_m = alpha*eq[m]+gamma; row max = t*e_max (t>0) else t*e_min -> K-split
// partials add with a COMMON max (no flash rescale needed).
// scal layout: [0..3] alpha_vi,gamma_vi,alpha_ir,gamma_ir;
//              float[8..11] = min e (bm), float[12..15] = max e (bm)
// ---------------------------------------------------------------------------

// kA: fused chansum (2-row tile + 1-row halo, recomputed) -> sobel -> e fields,
//     global min/max atomics, and (block 0,0) the alpha/gamma scalar reduction.
__global__ __launch_bounds__(256) void kA_prep(
    const float* __restrict__ vi, const float* __restrict__ ir,
    const float* __restrict__ wsx_vi, const float* __restrict__ wsy_vi,
    const float* __restrict__ wsx_q,  const float* __restrict__ wsy_q,
    const float* __restrict__ wsx_ir, const float* __restrict__ wsy_ir,
    const float* __restrict__ w1_vi, const float* __restrict__ w1_q,
    const float* __restrict__ b1_q,  const float* __restrict__ w1_ir,
    float* __restrict__ e, float* __restrict__ scal) {
    __shared__ float sv[256], si[256];           // 4 rows x 64 cols per mod
    __shared__ float Ad[8], Cv[8], Ci[8], Bq[8];
    const int b = blockIdx.y, rt = blockIdx.x, t = threadIdx.x;
    const int r0 = rt * 2;
    const float* xv = vi + b * 64 * 4096;
    const float* xi = ir + b * 64 * 4096;
    if (b == 0 && rt == 0 && t < 8) {
        float a = 0.f;
        for (int c = 0; c < 128; ++c) a += w1_q[t * 128 + c];
        float cv = 0.f, ci = 0.f;
        for (int c = 0; c < 64; ++c) { cv += w1_vi[t * 64 + c]; ci += w1_ir[t * 64 + c]; }
        Ad[t] = a; Cv[t] = cv; Ci[t] = ci; Bq[t] = b1_q[t];
    }
    #pragma unroll
    for (int k = 0; k < 2; ++k) {
        int id = t + k * 256;
        int mod = id >> 8;
        int entry = id & 255;
        int grow = r0 - 1 + (entry >> 6);
        int col = entry & 63;
        float acc = 0.f;
        if (grow >= 0 && grow < 64) {
            const float* x = (mod ? xi : xv) + grow * 64 + col;
            #pragma unroll 16
            for (int c = 0; c < 64; ++c) acc += x[c * 4096];
        }
        (mod ? si : sv)[entry] = acc;
    }
    __syncthreads();
    if (b == 0 && rt == 0 && t == 0) {
        float av = 0, gv = 0, ai = 0, gi = 0;
        for (int d = 0; d < 8; ++d) {
            av += Ad[d] * Cv[d]; gv += Bq[d] * Cv[d];
            ai += Ad[d] * Ci[d]; gi += Bq[d] * Ci[d];
        }
        scal[0] = av; scal[1] = gv; scal[2] = ai; scal[3] = gi;
    }
    if (t < 128) {
        int row = t >> 6, col = t & 63;
        int n = (r0 + row) * 64 + col;
        float nv[3][3], ni[3][3];
        #pragma unroll
        for (int di = 0; di < 3; ++di)
            #pragma unroll
            for (int dj = 0; dj < 3; ++dj) {
                int cc = col + dj - 1;
                bool in = (cc >= 0) & (cc < 64);
                int idx = (row + di) * 64 + (in ? cc : 0);
                nv[di][dj] = in ? sv[idx] : 0.f;
                ni[di][dj] = in ? si[idx] : 0.f;
            }
        float gxv = 0, gyv = 0, gxi = 0, gyi = 0, gxq = 0, gyq = 0;
        #pragma unroll
        for (int i = 0; i < 3; ++i)
            #pragma unroll
            for (int j = 0; j < 3; ++j) {
                int k = i * 3 + j;
                gxv += nv[i][j] * wsx_vi[k]; gyv += nv[i][j] * wsy_vi[k];
                gxi += ni[i][j] * wsx_ir[k]; gyi += ni[i][j] * wsy_ir[k];
                float q = nv[i][j] + ni[i][j];
                gxq += q * wsx_q[k]; gyq += q * wsy_q[k];
            }
        float ev = fabsf(gxv) + fabsf(gyv);
        float ei = fabsf(gxi) + fabsf(gyi);
        float eq = fabsf(gxq) + fabsf(gyq);
        e[(b * 3 + 0) * 4096 + n] = ev;
        e[(b * 3 + 1) * 4096 + n] = ei;
        e[(b * 3 + 2) * 4096 + n] = eq;
        float mnv = ev, mxv = ev, mni = ei, mxi = ei;
        for (int o = 32; o; o >>= 1) {
            mnv = fminf(mnv, __shfl_down(mnv, o));
            mxv = fmaxf(mxv, __shfl_down(mxv, o));
            mni = fminf(mni, __shfl_down(mni, o));
            mxi = fmaxf(mxi, __shfl_down(mxi, o));
        }
        if ((t & 63) == 0) {
            int* sc = (int*)scal;
            atomicMin(&sc[8  + b * 2 + 0], __float_as_int(mnv));
            atomicMax(&sc[12 + b * 2 + 0], __float_as_int(mxv));
            atomicMin(&sc[8  + b * 2 + 1], __float_as_int(mni));
            atomicMax(&sc[12 + b * 2 + 1], __float_as_int(mxi));
        }
    }
}

// k3: values 1x1 conv as MFMA GEMM: V[c,n] = W[c,:]x[:,n] + b.
// W staged in LDS (bf16, row-XOR-swizzled) -> A-frags via ds_read_b128.
// x loaded direct from global (16 scalar f32/thread), packed to bf16.
__global__ __launch_bounds__(256) void k3_values(
        const float* __restrict__ vi, const float* __restrict__ ir,
        const float* __restrict__ wv_vi, const float* __restrict__ bv_vi,
        const float* __restrict__ wv_ir, const float* __restrict__ bv_ir,
        __hip_bfloat16* __restrict__ Vc) {
    __shared__ __align__(16) char wlds[64 * 128];   // 64x64 bf16, swizzled rows
    const int bm = blockIdx.y, b = bm >> 1, mod = bm & 1;
    const float* wv = mod ? wv_ir : wv_vi;
    const float* bv = mod ? bv_ir : bv_vi;
    const float* x = (mod ? ir : vi) + b * (64 * 4096);
    const int tid = threadIdx.x;

    // stage W: thread t -> 16 consecutive f32 (row t>>2, cols (t&3)*16..+16)
    {
        const float* src = wv + tid * 16;
        int row = tid >> 2, colb = (tid & 3) * 32;   // byte offset of first col
        int pk[8];
        #pragma unroll
        for (int j = 0; j < 8; ++j)
            asm("v_cvt_pk_bf16_f32 %0, %1, %2" : "=v"(pk[j])
                : "v"(src[2 * j]), "v"(src[2 * j + 1]));
        int sw = (row & 7) << 4;
        i32x4 lo = {pk[0], pk[1], pk[2], pk[3]};
        i32x4 hi = {pk[4], pk[5], pk[6], pk[7]};
        *(i32x4*)(wlds + row * 128 + (colb ^ sw)) = lo;
        *(i32x4*)(wlds + row * 128 + ((colb + 16) ^ sw)) = hi;
    }
    __syncthreads();

    const int wvid = tid >> 6, lane = tid & 63;
    const int col = lane & 15, g = lane >> 4;
    const int n = blockIdx.x * 64 + wvid * 16 + col;

    // A-frags from LDS: W[cb*16+col][ks*32 + g*8 .. +8]
    bf16x8 afr[4][2];
    #pragma unroll
    for (int cb = 0; cb < 4; ++cb) {
        int row = cb * 16 + col;
        int sw = (row & 7) << 4;
        #pragma unroll
        for (int ks = 0; ks < 2; ++ks)
            afr[cb][ks] = *(const bf16x8*)(wlds + row * 128 + ((ks * 64 + g * 16) ^ sw));
    }

    // B-frags direct from global: x[(ks*32+g*8+j)*4096 + n]
    bf16x8 bfr[2];
    #pragma unroll
    for (int ks = 0; ks < 2; ++ks) {
        const float* xr = x + (ks * 32 + g * 8) * 4096 + n;
        int pk[4];
        #pragma unroll
        for (int j = 0; j < 4; ++j)
            asm("v_cvt_pk_bf16_f32 %0, %1, %2" : "=v"(pk[j])
                : "v"(xr[(2 * j) * 4096]), "v"(xr[(2 * j + 1) * 4096]));
        i32x4 bi = {pk[0], pk[1], pk[2], pk[3]};
        bfr[ks] = __builtin_bit_cast(bf16x8, bi);
    }

    // acc init = bias (C-operand of MFMA)
    f32x4 acc[4];
    #pragma unroll
    for (int cb = 0; cb < 4; ++cb) {
        #pragma unroll
        for (int r = 0; r < 4; ++r) acc[cb][r] = bv[cb * 16 + g * 4 + r];
    }
    #pragma unroll
    for (int ks = 0; ks < 2; ++ks)
        #pragma unroll
        for (int cb = 0; cb < 4; ++cb)
            acc[cb] = __builtin_amdgcn_mfma_f32_16x16x32_bf16(afr[cb][ks], bfr[ks], acc[cb], 0, 0, 0);

    __hip_bfloat16* outp = Vc + (size_t)(bm * 64) * 4096 + n;
    #pragma unroll
    for (int cb = 0; cb < 4; ++cb)
        #pragma unroll
        for (int r = 0; r < 4; ++r)
            outp[(cb * 16 + g * 4 + r) * 4096] = __float2bfloat16(acc[cb][r]);
}

// k4: O[c,m] = sum_n V[c,n] * 2^(t2_m*e[n] - M2_m);  Z via ones-MFMA.
// V K-chunk (64x1024 bf16, 128KB) + e chunk staged in LDS once (coalesced,
// XOR-swizzled rows); inner loop is LDS + VALU + MFMA only. Each block
// covers MT=4 m-tiles so V fragments are reused 4x per LDS read.
#define KLEN 1024
#define MT 4
__global__ __launch_bounds__(256, 1) void k4_attn(
        const float* __restrict__ e, const float* __restrict__ scal,
        const __hip_bfloat16* __restrict__ Vc,
        float* __restrict__ Opart, float* __restrict__ Zpart) {
    __shared__ __align__(16) char vbuf[64 * KLEN * 2];   // 128 KB swizzled
    __shared__ __align__(16) float elds[KLEN];           // 4 KB
    const int mt8 = blockIdx.x;   // 16 groups of 256 m
    const int bw  = blockIdx.y;   // b*2+which
    const int sp  = blockIdx.z;   // 4 K-splits
    const int b = bw >> 1, which = bw & 1;
    const int amod = which ? 0 : 1;
    const int vmod = which;
    const float* e_att = e + (b * 3 + amod) * 4096;
    const float* e_q   = e + (b * 3 + 2) * 4096;
    const float alpha = scal[which ? 0 : 2];
    const float gamma = scal[which ? 1 : 3];
    const float emn = scal[8  + b * 2 + amod];
    const float emx = scal[12 + b * 2 + amod];
    const short* Vg = (const short*)(Vc + (size_t)((b * 2 + vmod) * 64) * 4096);

    const int tid = threadIdx.x;
    #pragma unroll
    for (int k = 0; k < 32; ++k) {
        int id = tid + k * 256;
        int c = id >> 7, s = id & 127;
        bf16x8 v = *(const bf16x8*)(Vg + c * 4096 + sp * KLEN + s * 8);
        int dst = c * 2048 + ((s * 16) ^ ((c & 31) << 4));
        *(bf16x8*)(vbuf + dst) = v;
    }
    {
        f32x4 ev = *(const f32x4*)(e_att + sp * KLEN + tid * 4);
        *(f32x4*)(elds + tid * 4) = ev;
    }
    __syncthreads();

    const int wv = tid >> 6, lane = tid & 63;
    const int col = lane & 15, g = lane >> 4;
    const float L2E = 1.4426950408889634f;
    float t2[MT], nM2[MT];
    int mbase[MT];
    #pragma unroll
    for (int mt = 0; mt < MT; ++mt) {
        int m = mt8 * 256 + mt * 64 + wv * 16 + col;
        mbase[mt] = m;
        float t = alpha * e_q[m] + gamma;
        t2[mt]  = t * L2E;
        nM2[mt] = -((t > 0.f) ? t * emx : t * emn) * L2E;
    }

    f32x4 acc[MT][4] = {};
    f32x4 accz[MT] = {};
    bf16x8 ones;
    #pragma unroll
    for (int j = 0; j < 8; ++j) ones[j] = (short)0x3F80;

    for (int it = 0; it < KLEN / 32; ++it) {
        const int n0 = it * 32;
        bf16x8 af[4];
        #pragma unroll
        for (int cb = 0; cb < 4; ++cb) {
            int row = cb * 16 + col;
            int byte = row * 2048 + (((n0 + g * 8) * 2) ^ ((row & 31) << 4));
            af[cb] = *(const bf16x8*)(vbuf + byte);
        }
        f32x4 e0 = *(const f32x4*)(elds + n0 + g * 8);
        f32x4 e1 = *(const f32x4*)(elds + n0 + g * 8 + 4);
        #pragma unroll
        for (int mt = 0; mt < MT; ++mt) {
            float p[8];
            #pragma unroll
            for (int j = 0; j < 4; ++j) {
                float g0 = fmaf(e0[j], t2[mt], nM2[mt]);
                float g1 = fmaf(e1[j], t2[mt], nM2[mt]);
                asm("v_exp_f32 %0, %1" : "=v"(p[j])     : "v"(g0));
                asm("v_exp_f32 %0, %1" : "=v"(p[j + 4]) : "v"(g1));
            }
            int pk0, pk1, pk2, pk3;
            asm("v_cvt_pk_bf16_f32 %0, %1, %2" : "=v"(pk0) : "v"(p[0]), "v"(p[1]));
            asm("v_cvt_pk_bf16_f32 %0, %1, %2" : "=v"(pk1) : "v"(p[2]), "v"(p[3]));
            asm("v_cvt_pk_bf16_f32 %0, %1, %2" : "=v"(pk2) : "v"(p[4]), "v"(p[5]));
            asm("v_cvt_pk_bf16_f32 %0, %1, %2" : "=v"(pk3) : "v"(p[6]), "v"(p[7]));
            i32x4 pki = {pk0, pk1, pk2, pk3};
            bf16x8 bfrag = __builtin_bit_cast(bf16x8, pki);
            #pragma unroll
            for (int cb = 0; cb < 4; ++cb)
                acc[mt][cb] = __builtin_amdgcn_mfma_f32_16x16x32_bf16(af[cb], bfrag, acc[mt][cb], 0, 0, 0);
            accz[mt] = __builtin_amdgcn_mfma_f32_16x16x32_bf16(ones, bfrag, accz[mt], 0, 0, 0);
        }
    }

    float* opb = Opart + (size_t)((bw * 4 + sp) * 64) * 4096;
    #pragma unroll
    for (int mt = 0; mt < MT; ++mt) {
        float* op = opb + mbase[mt];
        #pragma unroll
        for (int cb = 0; cb < 4; ++cb) {
            int c = cb * 16 + g * 4;
            #pragma unroll
            for (int r = 0; r < 4; ++r) op[(c + r) * 4096] = acc[mt][cb][r];
        }
        if (lane < 16) Zpart[(bw * 4 + sp) * 4096 + mbase[mt]] = accz[mt][0];
    }
}

// k5: combine K-split partials and normalize (vectorized, S=4).
__global__ __launch_bounds__(256) void k5_combine(
        const float* __restrict__ Opart, const float* __restrict__ Zpart,
        float* __restrict__ out) {
    int bw = blockIdx.y; int b = bw >> 1, which = bw & 1;
    int idx = (blockIdx.x * 256 + threadIdx.x) * 4;
    int m = idx & 4095;
    f32x4 num = {}; f32x4 den = {};
    #pragma unroll
    for (int sp = 0; sp < 4; ++sp) {
        num += *(const f32x4*)(Opart + (size_t)((bw * 4 + sp) * 64) * 4096 + idx);
        den += *(const f32x4*)(Zpart + (bw * 4 + sp) * 4096 + m);
    }
    *(f32x4*)(out + which * (2 * 64 * 4096) + b * (64 * 4096) + idx) = num / den;
}

extern "C" void kernel_launch(void* const* d_in, const int* in_sizes, int n_in,
                              void* d_out, int out_size, void* d_ws, size_t ws_size,
                              hipStream_t stream) {
    const float* vi     = (const float*)d_in[0];
    const float* ir     = (const float*)d_in[1];
    const float* wsx_vi = (const float*)d_in[2];
    const float* wsy_vi = (const float*)d_in[3];
    const float* w1_vi  = (const float*)d_in[4];
    const float* wsx_q  = (const float*)d_in[6];
    const float* wsy_q  = (const float*)d_in[7];
    const float* w1_q   = (const float*)d_in[8];
    const float* b1_q   = (const float*)d_in[9];
    const float* wsx_ir = (const float*)d_in[10];
    const float* wsy_ir = (const float*)d_in[11];
    const float* w1_ir  = (const float*)d_in[12];
    const float* wv_vi  = (const float*)d_in[14];
    const float* bv_vi  = (const float*)d_in[15];
    const float* wv_ir  = (const float*)d_in[16];
    const float* bv_ir  = (const float*)d_in[17];
    (void)in_sizes; (void)n_in; (void)out_size;

    char* ws = (char*)d_ws;
    float* scal = (float*)ws;                              // 256 B
    float* e    = (float*)(ws + 256);                      // 96 KB
    __hip_bfloat16* Vc = (__hip_bfloat16*)(ws + 98560);    // 2 MB
    float* Opart = (float*)(ws + 2195712);                 // 16 MB (S=4)
    float* Zpart = (float*)(ws + 2195712 + 4ull * 4194304);
    float* out = (float*)d_out;
    (void)ws_size;

    hipMemsetAsync(ws + 32, 0x7F, 16, stream);   // min slots -> +big
    hipMemsetAsync(ws + 48, 0x00, 16, stream);   // max slots -> 0

    kA_prep<<<dim3(32, 2), 256, 0, stream>>>(vi, ir, wsx_vi, wsy_vi, wsx_q, wsy_q,
                                             wsx_ir, wsy_ir, w1_vi, w1_q, b1_q, w1_ir,
                                             e, scal);
    k3_values<<<dim3(64, 4), 256, 0, stream>>>(vi, ir, wv_vi, bv_vi, wv_ir, bv_ir, Vc);
    k4_attn<<<dim3(16, 4, 4), 256, 0, stream>>>(e, scal, Vc, Opart, Zpart);
    k5_combine<<<dim3(256, 4), 256, 0, stream>>>(Opart, Zpart, out);
}

// Round 5
// 45.850 us; speedup vs baseline: 2.8867x; 1.2985x over previous
//
#include <hip/hip_runtime.h>
#include <hip/hip_bf16.h>

typedef __attribute__((ext_vector_type(8))) short bf16x8;
typedef __attribute__((ext_vector_type(4))) float f32x4;
typedef __attribute__((ext_vector_type(4))) int   i32x4;

// ---------------------------------------------------------------------------
// B=2, C=64, H=W=64, N=4096, dk=8.
// Sobel weights are broadcast over [C,C,3,3] -> conv output = conv(chansum).
// Keys/queries affine in scalar field e[n]; softmax row m = softmax_n(t_m*e[n]),
// t_m = alpha*eq[m]+gamma; row max = t*e_max (t>0) else t*e_min -> K-split
// partials add with a COMMON max (no flash rescale needed).
// scal layout (floats): [0..3] alpha_vi,gamma_vi,alpha_ir,gamma_ir;
//   [16..143]  per-block min e: [bm=b*2+mod][rt=0..31]
//   [144..271] per-block max e: [bm][rt]
// ---------------------------------------------------------------------------

// kP: fused prep. Blocks 0..255: values 1x1-conv GEMM (k3). Blocks 256..319:
// chansum -> sobel -> e fields + per-block min/max slots + alpha/gamma.
__global__ __launch_bounds__(256) void kP_prep(
    const float* __restrict__ vi, const float* __restrict__ ir,
    const float* __restrict__ wsx_vi, const float* __restrict__ wsy_vi,
    const float* __restrict__ wsx_q,  const float* __restrict__ wsy_q,
    const float* __restrict__ wsx_ir, const float* __restrict__ wsy_ir,
    const float* __restrict__ w1_vi, const float* __restrict__ w1_q,
    const float* __restrict__ b1_q,  const float* __restrict__ w1_ir,
    const float* __restrict__ wv_vi, const float* __restrict__ bv_vi,
    const float* __restrict__ wv_ir, const float* __restrict__ bv_ir,
    float* __restrict__ e, float* __restrict__ scal,
    __hip_bfloat16* __restrict__ Vc) {
    const int t = threadIdx.x;
    if (blockIdx.x < 256) {
        // ---------------- values GEMM: V[c,n] = W[c,:] x[:,n] + b ----------
        __shared__ __align__(16) char wlds[64 * 128];   // 64x64 bf16 swizzled
        const int bm = blockIdx.x >> 6, nt = blockIdx.x & 63;
        const int b = bm >> 1, mod = bm & 1;
        const float* wv = mod ? wv_ir : wv_vi;
        const float* bv = mod ? bv_ir : bv_vi;
        const float* x = (mod ? ir : vi) + b * (64 * 4096);
        {
            const float* src = wv + t * 16;
            int row = t >> 2, colb = (t & 3) * 32;
            int pk[8];
            #pragma unroll
            for (int j = 0; j < 8; ++j)
                asm("v_cvt_pk_bf16_f32 %0, %1, %2" : "=v"(pk[j])
                    : "v"(src[2 * j]), "v"(src[2 * j + 1]));
            int sw = (row & 7) << 4;
            i32x4 lo = {pk[0], pk[1], pk[2], pk[3]};
            i32x4 hi = {pk[4], pk[5], pk[6], pk[7]};
            *(i32x4*)(wlds + row * 128 + (colb ^ sw)) = lo;
            *(i32x4*)(wlds + row * 128 + ((colb + 16) ^ sw)) = hi;
        }
        __syncthreads();
        const int wvid = t >> 6, lane = t & 63;
        const int col = lane & 15, g = lane >> 4;
        const int n = nt * 64 + wvid * 16 + col;
        bf16x8 afr[4][2];
        #pragma unroll
        for (int cb = 0; cb < 4; ++cb) {
            int row = cb * 16 + col;
            int sw = (row & 7) << 4;
            #pragma unroll
            for (int ks = 0; ks < 2; ++ks)
                afr[cb][ks] = *(const bf16x8*)(wlds + row * 128 + ((ks * 64 + g * 16) ^ sw));
        }
        bf16x8 bfr[2];
        #pragma unroll
        for (int ks = 0; ks < 2; ++ks) {
            const float* xr = x + (ks * 32 + g * 8) * 4096 + n;
            int pk[4];
            #pragma unroll
            for (int j = 0; j < 4; ++j)
                asm("v_cvt_pk_bf16_f32 %0, %1, %2" : "=v"(pk[j])
                    : "v"(xr[(2 * j) * 4096]), "v"(xr[(2 * j + 1) * 4096]));
            i32x4 bi = {pk[0], pk[1], pk[2], pk[3]};
            bfr[ks] = __builtin_bit_cast(bf16x8, bi);
        }
        f32x4 acc[4];
        #pragma unroll
        for (int cb = 0; cb < 4; ++cb)
            #pragma unroll
            for (int r = 0; r < 4; ++r) acc[cb][r] = bv[cb * 16 + g * 4 + r];
        #pragma unroll
        for (int ks = 0; ks < 2; ++ks)
            #pragma unroll
            for (int cb = 0; cb < 4; ++cb)
                acc[cb] = __builtin_amdgcn_mfma_f32_16x16x32_bf16(afr[cb][ks], bfr[ks], acc[cb], 0, 0, 0);
        __hip_bfloat16* outp = Vc + (size_t)(bm * 64) * 4096 + n;
        #pragma unroll
        for (int cb = 0; cb < 4; ++cb)
            #pragma unroll
            for (int r = 0; r < 4; ++r)
                outp[(cb * 16 + g * 4 + r) * 4096] = __float2bfloat16(acc[cb][r]);
    } else {
        // ---------------- chansum -> sobel -> e, min/max slots --------------
        __shared__ float sv[256], si[256];       // 4 rows x 64 cols per mod
        __shared__ float Ad[8], Cv[8], Ci[8], Bq[8];
        __shared__ float mmred[8];
        const int id = blockIdx.x - 256;
        const int rt = id & 31, b = id >> 5;
        const int r0 = rt * 2;
        const float* xv = vi + b * 64 * 4096;
        const float* xi = ir + b * 64 * 4096;
        if (b == 0 && rt == 0 && t < 8) {
            float a = 0.f;
            for (int c = 0; c < 128; ++c) a += w1_q[t * 128 + c];
            float cv = 0.f, ci = 0.f;
            for (int c = 0; c < 64; ++c) { cv += w1_vi[t * 64 + c]; ci += w1_ir[t * 64 + c]; }
            Ad[t] = a; Cv[t] = cv; Ci[t] = ci; Bq[t] = b1_q[t];
        }
        #pragma unroll
        for (int k = 0; k < 2; ++k) {
            int id2 = t + k * 256;
            int mod = id2 >> 8;
            int entry = id2 & 255;
            int grow = r0 - 1 + (entry >> 6);
            int col = entry & 63;
            float acc = 0.f;
            if (grow >= 0 && grow < 64) {
                const float* x = (mod ? xi : xv) + grow * 64 + col;
                #pragma unroll 16
                for (int c = 0; c < 64; ++c) acc += x[c * 4096];
            }
            (mod ? si : sv)[entry] = acc;
        }
        __syncthreads();
        if (b == 0 && rt == 0 && t == 0) {
            float av = 0, gv = 0, ai = 0, gi = 0;
            for (int d = 0; d < 8; ++d) {
                av += Ad[d] * Cv[d]; gv += Bq[d] * Cv[d];
                ai += Ad[d] * Ci[d]; gi += Bq[d] * Ci[d];
            }
            scal[0] = av; scal[1] = gv; scal[2] = ai; scal[3] = gi;
        }
        if (t < 128) {
            int row = t >> 6, col = t & 63;
            int n = (r0 + row) * 64 + col;
            float nv[3][3], ni[3][3];
            #pragma unroll
            for (int di = 0; di < 3; ++di)
                #pragma unroll
                for (int dj = 0; dj < 3; ++dj) {
                    int cc = col + dj - 1;
                    bool in = (cc >= 0) & (cc < 64);
                    int idx = (row + di) * 64 + (in ? cc : 0);
                    nv[di][dj] = in ? sv[idx] : 0.f;
                    ni[di][dj] = in ? si[idx] : 0.f;
                }
            float gxv = 0, gyv = 0, gxi = 0, gyi = 0, gxq = 0, gyq = 0;
            #pragma unroll
            for (int i = 0; i < 3; ++i)
                #pragma unroll
                for (int j = 0; j < 3; ++j) {
                    int k = i * 3 + j;
                    gxv += nv[i][j] * wsx_vi[k]; gyv += nv[i][j] * wsy_vi[k];
                    gxi += ni[i][j] * wsx_ir[k]; gyi += ni[i][j] * wsy_ir[k];
                    float q = nv[i][j] + ni[i][j];
                    gxq += q * wsx_q[k]; gyq += q * wsy_q[k];
                }
            float ev = fabsf(gxv) + fabsf(gyv);
            float ei = fabsf(gxi) + fabsf(gyi);
            float eq = fabsf(gxq) + fabsf(gyq);
            e[(b * 3 + 0) * 4096 + n] = ev;
            e[(b * 3 + 1) * 4096 + n] = ei;
            e[(b * 3 + 2) * 4096 + n] = eq;
            float mnv = ev, mxv = ev, mni = ei, mxi = ei;
            for (int o = 32; o; o >>= 1) {
                mnv = fminf(mnv, __shfl_down(mnv, o));
                mxv = fmaxf(mxv, __shfl_down(mxv, o));
                mni = fminf(mni, __shfl_down(mni, o));
                mxi = fmaxf(mxi, __shfl_down(mxi, o));
            }
            if ((t & 63) == 0) {
                int w = t >> 6;
                mmred[w * 4 + 0] = mnv; mmred[w * 4 + 1] = mxv;
                mmred[w * 4 + 2] = mni; mmred[w * 4 + 3] = mxi;
            }
        }
        __syncthreads();
        if (t == 0) {
            float* bmn = scal + 16;
            float* bmx = scal + 144;
            bmn[(b * 2 + 0) * 32 + rt] = fminf(mmred[0], mmred[4]);
            bmx[(b * 2 + 0) * 32 + rt] = fmaxf(mmred[1], mmred[5]);
            bmn[(b * 2 + 1) * 32 + rt] = fminf(mmred[2], mmred[6]);
            bmx[(b * 2 + 1) * 32 + rt] = fmaxf(mmred[3], mmred[7]);
        }
    }
}

// k4: O[c,m] = sum_n V[c,n] * 2^(t2_m*e[n] - M2_m);  Z via ones-MFMA.
// V K-chunk (64x1024 bf16, 128KB) + e chunk staged in LDS (XOR-swizzled);
// inner loop LDS+VALU+MFMA only; MT=4 m-tiles reuse each V fragment.
#define KLEN 1024
#define MT 4
__global__ __launch_bounds__(256, 1) void k4_attn(
        const float* __restrict__ e, const float* __restrict__ scal,
        const __hip_bfloat16* __restrict__ Vc,
        float* __restrict__ Opart, float* __restrict__ Zpart) {
    __shared__ __align__(16) char vbuf[64 * KLEN * 2];   // 128 KB swizzled
    __shared__ __align__(16) float elds[KLEN];           // 4 KB
    const int mt8 = blockIdx.x;   // 16 groups of 256 m
    const int bw  = blockIdx.y;   // b*2+which
    const int sp  = blockIdx.z;   // 4 K-splits
    const int b = bw >> 1, which = bw & 1;
    const int amod = which ? 0 : 1;
    const int vmod = which;
    const float* e_att = e + (b * 3 + amod) * 4096;
    const float* e_q   = e + (b * 3 + 2) * 4096;
    const float alpha = scal[which ? 0 : 2];
    const float gamma = scal[which ? 1 : 3];
    const short* Vg = (const short*)(Vc + (size_t)((b * 2 + vmod) * 64) * 4096);

    const int tid = threadIdx.x;
    const int wv = tid >> 6, lane = tid & 63;

    // global min/max of e field: lane-parallel reduce of 32 per-block slots
    float emn = scal[16  + (b * 2 + amod) * 32 + (lane & 31)];
    float emx = scal[144 + (b * 2 + amod) * 32 + (lane & 31)];
    #pragma unroll
    for (int o = 16; o; o >>= 1) {
        emn = fminf(emn, __shfl_xor(emn, o));
        emx = fmaxf(emx, __shfl_xor(emx, o));
    }

    #pragma unroll
    for (int k = 0; k < 32; ++k) {
        int id = tid + k * 256;
        int c = id >> 7, s = id & 127;
        bf16x8 v = *(const bf16x8*)(Vg + c * 4096 + sp * KLEN + s * 8);
        int dst = c * 2048 + ((s * 16) ^ ((c & 31) << 4));
        *(bf16x8*)(vbuf + dst) = v;
    }
    {
        f32x4 ev = *(const f32x4*)(e_att + sp * KLEN + tid * 4);
        *(f32x4*)(elds + tid * 4) = ev;
    }
    __syncthreads();

    const int col = lane & 15, g = lane >> 4;
    const float L2E = 1.4426950408889634f;
    float t2[MT], nM2[MT];
    int mbase[MT];
    #pragma unroll
    for (int mt = 0; mt < MT; ++mt) {
        int m = mt8 * 256 + mt * 64 + wv * 16 + col;
        mbase[mt] = m;
        float t = alpha * e_q[m] + gamma;
        t2[mt]  = t * L2E;
        nM2[mt] = -((t > 0.f) ? t * emx : t * emn) * L2E;
    }

    f32x4 acc[MT][4] = {};
    f32x4 accz[MT] = {};
    bf16x8 ones;
    #pragma unroll
    for (int j = 0; j < 8; ++j) ones[j] = (short)0x3F80;

    for (int it = 0; it < KLEN / 32; ++it) {
        const int n0 = it * 32;
        bf16x8 af[4];
        #pragma unroll
        for (int cb = 0; cb < 4; ++cb) {
            int row = cb * 16 + col;
            int byte = row * 2048 + (((n0 + g * 8) * 2) ^ ((row & 31) << 4));
            af[cb] = *(const bf16x8*)(vbuf + byte);
        }
        f32x4 e0 = *(const f32x4*)(elds + n0 + g * 8);
        f32x4 e1 = *(const f32x4*)(elds + n0 + g * 8 + 4);
        #pragma unroll
        for (int mt = 0; mt < MT; ++mt) {
            float p[8];
            #pragma unroll
            for (int j = 0; j < 4; ++j) {
                float g0 = fmaf(e0[j], t2[mt], nM2[mt]);
                float g1 = fmaf(e1[j], t2[mt], nM2[mt]);
                asm("v_exp_f32 %0, %1" : "=v"(p[j])     : "v"(g0));
                asm("v_exp_f32 %0, %1" : "=v"(p[j + 4]) : "v"(g1));
            }
            int pk0, pk1, pk2, pk3;
            asm("v_cvt_pk_bf16_f32 %0, %1, %2" : "=v"(pk0) : "v"(p[0]), "v"(p[1]));
            asm("v_cvt_pk_bf16_f32 %0, %1, %2" : "=v"(pk1) : "v"(p[2]), "v"(p[3]));
            asm("v_cvt_pk_bf16_f32 %0, %1, %2" : "=v"(pk2) : "v"(p[4]), "v"(p[5]));
            asm("v_cvt_pk_bf16_f32 %0, %1, %2" : "=v"(pk3) : "v"(p[6]), "v"(p[7]));
            i32x4 pki = {pk0, pk1, pk2, pk3};
            bf16x8 bfrag = __builtin_bit_cast(bf16x8, pki);
            #pragma unroll
            for (int cb = 0; cb < 4; ++cb)
                acc[mt][cb] = __builtin_amdgcn_mfma_f32_16x16x32_bf16(af[cb], bfrag, acc[mt][cb], 0, 0, 0);
            accz[mt] = __builtin_amdgcn_mfma_f32_16x16x32_bf16(ones, bfrag, accz[mt], 0, 0, 0);
        }
    }

    float* opb = Opart + (size_t)((bw * 4 + sp) * 64) * 4096;
    #pragma unroll
    for (int mt = 0; mt < MT; ++mt) {
        float* op = opb + mbase[mt];
        #pragma unroll
        for (int cb = 0; cb < 4; ++cb) {
            int c = cb * 16 + g * 4;
            #pragma unroll
            for (int r = 0; r < 4; ++r) op[(c + r) * 4096] = acc[mt][cb][r];
        }
        if (lane < 16) Zpart[(bw * 4 + sp) * 4096 + mbase[mt]] = accz[mt][0];
    }
}

// k5: combine K-split partials and normalize (vectorized, S=4).
__global__ __launch_bounds__(256) void k5_combine(
        const float* __restrict__ Opart, const float* __restrict__ Zpart,
        float* __restrict__ out) {
    int bw = blockIdx.y; int b = bw >> 1, which = bw & 1;
    int idx = (blockIdx.x * 256 + threadIdx.x) * 4;
    int m = idx & 4095;
    f32x4 num = {}; f32x4 den = {};
    #pragma unroll
    for (int sp = 0; sp < 4; ++sp) {
        num += *(const f32x4*)(Opart + (size_t)((bw * 4 + sp) * 64) * 4096 + idx);
        den += *(const f32x4*)(Zpart + (bw * 4 + sp) * 4096 + m);
    }
    *(f32x4*)(out + which * (2 * 64 * 4096) + b * (64 * 4096) + idx) = num / den;
}

extern "C" void kernel_launch(void* const* d_in, const int* in_sizes, int n_in,
                              void* d_out, int out_size, void* d_ws, size_t ws_size,
                              hipStream_t stream) {
    const float* vi     = (const float*)d_in[0];
    const float* ir     = (const float*)d_in[1];
    const float* wsx_vi = (const float*)d_in[2];
    const float* wsy_vi = (const float*)d_in[3];
    const float* w1_vi  = (const float*)d_in[4];
    const float* wsx_q  = (const float*)d_in[6];
    const float* wsy_q  = (const float*)d_in[7];
    const float* w1_q   = (const float*)d_in[8];
    const float* b1_q   = (const float*)d_in[9];
    const float* wsx_ir = (const float*)d_in[10];
    const float* wsy_ir = (const float*)d_in[11];
    const float* w1_ir  = (const float*)d_in[12];
    const float* wv_vi  = (const float*)d_in[14];
    const float* bv_vi  = (const float*)d_in[15];
    const float* wv_ir  = (const float*)d_in[16];
    const float* bv_ir  = (const float*)d_in[17];
    (void)in_sizes; (void)n_in; (void)out_size;

    char* ws = (char*)d_ws;
    float* scal = (float*)ws;                              // 1088 B used
    float* e    = (float*)(ws + 1280);                     // 96 KB
    __hip_bfloat16* Vc = (__hip_bfloat16*)(ws + 99584);    // 2 MB
    float* Opart = (float*)(ws + 2196736);                 // 16 MB
    float* Zpart = (float*)(ws + 2196736 + 4ull * 4194304);
    float* out = (float*)d_out;
    (void)ws_size;

    kP_prep<<<dim3(320), 256, 0, stream>>>(vi, ir, wsx_vi, wsy_vi, wsx_q, wsy_q,
                                           wsx_ir, wsy_ir, w1_vi, w1_q, b1_q, w1_ir,
                                           wv_vi, bv_vi, wv_ir, bv_ir, e, scal, Vc);
    k4_attn<<<dim3(16, 4, 4), 256, 0, stream>>>(e, scal, Vc, Opart, Zpart);
    k5_combine<<<dim3(256, 4), 256, 0, stream>>>(Opart, Zpart, out);
}